// Round 1
// 721.000 us; speedup vs baseline: 1.0158x; 1.0158x over previous
//
#include <hip/hip_runtime.h>
#include <hip/hip_bf16.h>
#include <math.h>

// Problem constants
#define HID   2048
#define NEXP  8
#define IMOE  1408
#define ISH   5632
#define NTOK  1024
#define NASSIGN 2048   // NTOK * TOP_K

typedef __bf16 bf16;
typedef __bf16 bf16x8 __attribute__((ext_vector_type(8)));
typedef float  f32x4  __attribute__((ext_vector_type(4)));

__device__ inline bf16x8 cvt8(f32x4 a, f32x4 b) {
  bf16x8 r;
  r[0] = (bf16)a[0]; r[1] = (bf16)a[1]; r[2] = (bf16)a[2]; r[3] = (bf16)a[3];
  r[4] = (bf16)b[0]; r[5] = (bf16)b[1]; r[6] = (bf16)b[2]; r[7] = (bf16)b[3];
  return r;
}

// async 16B/lane global->LDS. lptr must be wave-uniform; HW adds lane*16.
__device__ inline void async16(const bf16* g, bf16* l) {
  __builtin_amdgcn_global_load_lds(
      (const __attribute__((address_space(1))) void*)g,
      (__attribute__((address_space(3))) void*)l, 16, 0, 0);
}

// ---------------------------------------------------------------------------
// fp32 -> bf16 conversion, single streaming pass.
// Grid-stride, 2048 blocks, 16 elems/thread/iter (64B NT read, 32B write).
// Segment boundaries in 16-elem chunks:
//   x 131072 | w1 2883584 | w2 1441792 | sgu 1441792 | sdw 720896
// ---------------------------------------------------------------------------
#define C16_P0 131072L
#define C16_P1 3014656L
#define C16_P2 4456448L
#define C16_P3 5898240L
#define C16_P4 6619136L   // total 16-elem chunks
#define CVT_BLOCKS 2048
#define CVT_STRIDE ((long)CVT_BLOCKS * 256)

__global__ __launch_bounds__(256) void convert_kernel(
    const float* __restrict__ x, const float* __restrict__ w1,
    const float* __restrict__ w2, const float* __restrict__ sgu,
    const float* __restrict__ sdw,
    bf16* __restrict__ xb, bf16* __restrict__ w1b, bf16* __restrict__ w2b,
    bf16* __restrict__ sgub, bf16* __restrict__ sdwb)
{
  for (long g = (long)blockIdx.x * 256 + threadIdx.x; g < C16_P4; g += CVT_STRIDE) {
    const float* s; bf16* d; long off;
    if      (g < C16_P0) { s = x;   d = xb;   off = g; }
    else if (g < C16_P1) { s = w1;  d = w1b;  off = g - C16_P0; }
    else if (g < C16_P2) { s = w2;  d = w2b;  off = g - C16_P1; }
    else if (g < C16_P3) { s = sgu; d = sgub; off = g - C16_P2; }
    else                 { s = sdw; d = sdwb; off = g - C16_P3; }
    long e = off * 16;
    f32x4 a = __builtin_nontemporal_load((const f32x4*)(s + e));
    f32x4 b = __builtin_nontemporal_load((const f32x4*)(s + e + 4));
    f32x4 c = __builtin_nontemporal_load((const f32x4*)(s + e + 8));
    f32x4 dd = __builtin_nontemporal_load((const f32x4*)(s + e + 12));
    *(bf16x8*)(d + e)     = cvt8(a, b);
    *(bf16x8*)(d + e + 8) = cvt8(c, dd);
  }
}

// ---------------------------------------------------------------------------
// Router (fp32): top-2 renormalized = sigmoid(l0-l1); shared sigmoid gate.
// ---------------------------------------------------------------------------
__global__ __launch_bounds__(256) void router_kernel(
    const float* __restrict__ x, const float* __restrict__ gate_w,
    const float* __restrict__ sgate_w, float* __restrict__ sg,
    int2* __restrict__ tk_idx, float2* __restrict__ tk_w)
{
  const int t = blockIdx.x;
  const float* xr = x + (long)t * HID;
  float p[9];
#pragma unroll
  for (int i = 0; i < 9; i++) p[i] = 0.f;
  for (int c = threadIdx.x; c < HID; c += 256) {
    float xv = xr[c];
#pragma unroll
    for (int e = 0; e < 8; e++) p[e] += xv * gate_w[e * HID + c];
    p[8] += xv * sgate_w[c];
  }
#pragma unroll
  for (int i = 0; i < 9; i++)
    for (int off = 32; off > 0; off >>= 1)
      p[i] += __shfl_xor(p[i], off, 64);
  __shared__ float red[4][9];
  const int wave = threadIdx.x >> 6, lane = threadIdx.x & 63;
  if (lane == 0)
    for (int i = 0; i < 9; i++) red[wave][i] = p[i];
  __syncthreads();
  if (threadIdx.x == 0) {
    float l[9];
    for (int i = 0; i < 9; i++)
      l[i] = red[0][i] + red[1][i] + red[2][i] + red[3][i];
    int i0 = 0;
    for (int e = 1; e < 8; e++) if (l[e] > l[i0]) i0 = e;
    int i1 = -1;
    for (int e = 0; e < 8; e++) {
      if (e == i0) continue;
      if (i1 < 0 || l[e] > l[i1]) i1 = e;
    }
    float w0 = 1.f / (1.f + __expf(l[i1] - l[i0]));
    tk_idx[t] = make_int2(i0, i1);
    tk_w[t]   = make_float2(w0, 1.f - w0);
    sg[t]     = 1.f / (1.f + __expf(-l[8]));
  }
}

__global__ __launch_bounds__(256) void scatter_kernel(
    const int2* __restrict__ tk_idx, const float2* __restrict__ tk_w,
    int* __restrict__ offs, int* __restrict__ s_tok, float* __restrict__ s_wgt)
{
  __shared__ int cnt[8], pos[8];
  if (threadIdx.x < 8) cnt[threadIdx.x] = 0;
  __syncthreads();
  for (int a = threadIdx.x; a < NASSIGN; a += 256) {
    int2 ii = tk_idx[a >> 1];
    int e = (a & 1) ? ii.y : ii.x;
    atomicAdd(&cnt[e], 1);
  }
  __syncthreads();
  if (threadIdx.x == 0) {
    int s = 0;
    for (int e = 0; e < 8; e++) { offs[e] = s; pos[e] = s; s += cnt[e]; }
    offs[8] = s;
  }
  __syncthreads();
  for (int a = threadIdx.x; a < NASSIGN; a += 256) {
    int t = a >> 1;
    int2 ii = tk_idx[t];
    float2 ww = tk_w[t];
    int   e = (a & 1) ? ii.y : ii.x;
    float w = (a & 1) ? ww.y : ww.x;
    int pp = atomicAdd(&pos[e], 1);
    s_tok[pp] = t;
    s_wgt[pp] = w;
  }
}

// ---------------------------------------------------------------------------
// Fused gate_up GEMM + SiLU*mul (m97-style): bf16 global_load_lds width=16,
// single LDS buffer, 2 barriers/step, BK=32, 16x16x32 MFMA.
// LDS tiles unpadded [rows][32] bf16; 16B chunks XOR-swizzled by (row&3)
// on the GLOBAL side so frag ds_read_b128 is conflict-free.
// B tile = 128 rows: [0..63]=gate, [64..127]=up for 64 output h-cols.
// ---------------------------------------------------------------------------
template<int BM, bool GROUPED>
__global__ __launch_bounds__(256) void gemm_gu(
    const bf16* __restrict__ X,
    const bf16* __restrict__ Wg_base, long expert_stride, long up_off,
    bf16* __restrict__ Hout, int hstride,
    const int* __restrict__ offs, const int* __restrict__ s_tok,
    const bf16* __restrict__ zpad)
{
  static_assert(BM == 64 || BM == 128, "BM");
  constexpr int K = HID, NS = K / 32;
  constexpr int AIP = BM / 64;   // A staging insts per wave
  constexpr int AF  = BM / 32;   // A frags per wave
  const int n0 = blockIdx.x * 64;
  const int e  = GROUPED ? blockIdx.z : 0;
  int m_base, m_end;
  if (GROUPED) {
    m_base = offs[e] + blockIdx.y * BM;
    m_end  = offs[e + 1];
    if (m_base >= m_end) return;
  } else { m_base = blockIdx.y * BM; m_end = NTOK; }
  const bf16* Wg = Wg_base + (long)e * expert_stride;

  __shared__ __attribute__((aligned(16))) bf16 As[BM * 32];
  __shared__ __attribute__((aligned(16))) bf16 Bs[128 * 32];

  const int tid = threadIdx.x, wave = tid >> 6, lane = tid & 63;

  // staging pointers: inst covers 16 rows; lane -> (row=l>>2, pos=l&3),
  // fetch global chunk g = pos ^ (row&3)  (swizzle)
  const bf16* pa[AIP]; bf16* la[AIP];
#pragma unroll
  for (int q = 0; q < AIP; q++) {
    int ia  = wave * AIP + q;
    int rl  = ia * 16 + (lane >> 2);
    int gch = (lane & 3) ^ (rl & 3);
    const bf16* src;
    if (GROUPED) {
      int gr  = m_base + rl;
      int tok = (gr < m_end) ? s_tok[gr] : -1;
      src = (tok >= 0) ? X + (long)tok * K : zpad;
    } else src = X + (long)(m_base + rl) * K;
    pa[q] = src + gch * 8;
    la[q] = As + ia * 512;
  }
  const bf16* pb[2]; bf16* lb[2];
#pragma unroll
  for (int q = 0; q < 2; q++) {
    int ib  = wave * 2 + q;
    int rl  = ib * 16 + (lane >> 2);
    int gch = (lane & 3) ^ (rl & 3);
    const bf16* src = (rl < 64) ? Wg + (long)(n0 + rl) * K
                                : Wg + up_off + (long)(n0 + rl - 64) * K;
    pb[q] = src + gch * 8;
    lb[q] = Bs + ib * 512;
  }

  const int wm = wave >> 1, wn = wave & 1;
  f32x4 accg[AF][2], accu[AF][2];
#pragma unroll
  for (int i = 0; i < AF; i++)
#pragma unroll
    for (int j = 0; j < 2; j++) {
      accg[i][j] = f32x4{0.f, 0.f, 0.f, 0.f};
      accu[i][j] = f32x4{0.f, 0.f, 0.f, 0.f};
    }

  const int fr = lane & 15, cch = lane >> 4;   // frag row, k-chunk

  for (int s = 0; s < NS; s++) {
    __syncthreads();            // previous consumers done with LDS
#pragma unroll
    for (int q = 0; q < AIP; q++) { async16(pa[q], la[q]); pa[q] += 32; }
#pragma unroll
    for (int q = 0; q < 2;   q++) { async16(pb[q], lb[q]); pb[q] += 32; }
    asm volatile("s_waitcnt vmcnt(0)" ::: "memory");
    __syncthreads();            // staged tile visible to all waves

    bf16x8 a[AF], bg[2], bu[2];
#pragma unroll
    for (int i = 0; i < AF; i++) {
      int ar = wm * (AF * 16) + i * 16 + fr;
      a[i] = *(const bf16x8*)&As[ar * 32 + ((cch ^ (ar & 3)) * 8)];
    }
#pragma unroll
    for (int j = 0; j < 2; j++) {
      int br = wn * 32 + j * 16 + fr;
      int ur = 64 + br;
      bg[j] = *(const bf16x8*)&Bs[br * 32 + ((cch ^ (br & 3)) * 8)];
      bu[j] = *(const bf16x8*)&Bs[ur * 32 + ((cch ^ (ur & 3)) * 8)];
    }
#pragma unroll
    for (int i = 0; i < AF; i++)
#pragma unroll
      for (int j = 0; j < 2; j++) {
        accg[i][j] = __builtin_amdgcn_mfma_f32_16x16x32_bf16(a[i], bg[j], accg[i][j], 0, 0, 0);
        accu[i][j] = __builtin_amdgcn_mfma_f32_16x16x32_bf16(a[i], bu[j], accu[i][j], 0, 0, 0);
      }
  }
  // epilogue: h = silu(g)*u  (C/D: row=(lane>>4)*4+r, col=lane&15)
#pragma unroll
  for (int i = 0; i < AF; i++)
#pragma unroll
    for (int j = 0; j < 2; j++)
#pragma unroll
      for (int r = 0; r < 4; r++) {
        int row  = wm * (AF * 16) + i * 16 + (lane >> 4) * 4 + r;
        int grow = m_base + row;
        if (GROUPED && grow >= m_end) continue;
        int col = wn * 32 + j * 16 + (lane & 15);
        float g = accg[i][j][r], u = accu[i][j][r];
        float h = g / (1.f + __expf(-g)) * u;
        Hout[(long)grow * hstride + n0 + col] = (bf16)h;
      }
}

// ---------------------------------------------------------------------------
// Down GEMM: out[target(m), n] += scale(m) * (H . W^T)[m,n]
// Same m97 staging. BM x 128 tile. atomicAdd fp32 epilogue.
// GROUPED: blockIdx.z = e*KSPLIT + ks.   !GROUPED: blockIdx.z = ks.
// ---------------------------------------------------------------------------
template<int BM, bool GROUPED, int KSPLIT>
__global__ __launch_bounds__(256) void gemm_down(
    const bf16* __restrict__ Hin, int K,
    const bf16* __restrict__ W_base, long expert_stride,
    float* __restrict__ Out, const float* __restrict__ scale,
    const int* __restrict__ offs, const int* __restrict__ s_tok)
{
  static_assert(BM == 64 || BM == 128, "BM");
  constexpr int AIP = BM / 64, AF = BM / 32;
  const int n0 = blockIdx.x * 128;
  int e = 0, ks, m_base, m_end;
  if (GROUPED) {
    e  = blockIdx.z / KSPLIT;
    ks = blockIdx.z % KSPLIT;
    m_base = offs[e] + blockIdx.y * BM;
    m_end  = offs[e + 1];
    if (m_base >= m_end) return;
  } else {
    ks = blockIdx.z;
    m_base = blockIdx.y * BM;
    m_end  = NTOK;
  }
  const int k_lo = ks * (K / KSPLIT);
  const int NS   = (K / KSPLIT) / 32;
  const bf16* W = W_base + (long)e * expert_stride;

  __shared__ __attribute__((aligned(16))) bf16 As[BM * 32];
  __shared__ __attribute__((aligned(16))) bf16 Bs[128 * 32];

  const int tid = threadIdx.x, wave = tid >> 6, lane = tid & 63;

  const bf16* pa[AIP]; bf16* la[AIP];
#pragma unroll
  for (int q = 0; q < AIP; q++) {
    int ia  = wave * AIP + q;
    int rl  = ia * 16 + (lane >> 2);
    int gch = (lane & 3) ^ (rl & 3);
    pa[q] = Hin + (long)(m_base + rl) * K + k_lo + gch * 8;  // rows compact; tail pad ok
    la[q] = As + ia * 512;
  }
  const bf16* pb[2]; bf16* lb[2];
#pragma unroll
  for (int q = 0; q < 2; q++) {
    int ib  = wave * 2 + q;
    int rl  = ib * 16 + (lane >> 2);
    int gch = (lane & 3) ^ (rl & 3);
    pb[q] = W + (long)(n0 + rl) * K + k_lo + gch * 8;
    lb[q] = Bs + ib * 512;
  }

  const int wm = wave >> 1, wn = wave & 1;
  f32x4 acc[AF][4];
#pragma unroll
  for (int i = 0; i < AF; i++)
#pragma unroll
    for (int j = 0; j < 4; j++) acc[i][j] = f32x4{0.f, 0.f, 0.f, 0.f};

  const int fr = lane & 15, cch = lane >> 4;

  for (int s = 0; s < NS; s++) {
    __syncthreads();
#pragma unroll
    for (int q = 0; q < AIP; q++) { async16(pa[q], la[q]); pa[q] += 32; }
#pragma unroll
    for (int q = 0; q < 2;   q++) { async16(pb[q], lb[q]); pb[q] += 32; }
    asm volatile("s_waitcnt vmcnt(0)" ::: "memory");
    __syncthreads();

    bf16x8 a[AF], b[4];
#pragma unroll
    for (int i = 0; i < AF; i++) {
      int ar = wm * (AF * 16) + i * 16 + fr;
      a[i] = *(const bf16x8*)&As[ar * 32 + ((cch ^ (ar & 3)) * 8)];
    }
#pragma unroll
    for (int j = 0; j < 4; j++) {
      int br = wn * 64 + j * 16 + fr;
      b[j] = *(const bf16x8*)&Bs[br * 32 + ((cch ^ (br & 3)) * 8)];
    }
#pragma unroll
    for (int i = 0; i < AF; i++)
#pragma unroll
      for (int j = 0; j < 4; j++)
        acc[i][j] = __builtin_amdgcn_mfma_f32_16x16x32_bf16(a[i], b[j], acc[i][j], 0, 0, 0);
  }
#pragma unroll
  for (int i = 0; i < AF; i++)
#pragma unroll
    for (int j = 0; j < 4; j++)
#pragma unroll
      for (int r = 0; r < 4; r++) {
        int row  = wm * (AF * 16) + i * 16 + (lane >> 4) * 4 + r;
        int grow = m_base + row;
        if (GROUPED && grow >= m_end) continue;
        int col = wn * 64 + j * 16 + (lane & 15);
        float sc = scale[grow];
        int target = GROUPED ? s_tok[grow] : grow;
        atomicAdd(&Out[(long)target * HID + n0 + col], sc * acc[i][j][r]);
      }
}

// ---------------------------------------------------------------------------
extern "C" void kernel_launch(void* const* d_in, const int* in_sizes, int n_in,
                              void* d_out, int out_size, void* d_ws, size_t ws_size,
                              hipStream_t stream)
{
  const float* x    = (const float*)d_in[0];
  const float* gw   = (const float*)d_in[1];
  const float* w1   = (const float*)d_in[2];
  const float* w2   = (const float*)d_in[3];
  const float* sguw = (const float*)d_in[4];
  const float* sdw  = (const float*)d_in[5];
  const float* sgw  = (const float*)d_in[6];
  float* out = (float*)d_out;

  char* ws = (char*)d_ws;
  size_t off = 0;
  auto alloc = [&](size_t bytes) {
    void* p = ws + off;
    off = (off + bytes + 255) & ~(size_t)255;
    return p;
  };
  float*  sg    = (float*)alloc(NTOK * 4);
  int2*   tki   = (int2*)alloc(NTOK * 8);
  float2* tkw   = (float2*)alloc(NTOK * 8);
  int*    offs  = (int*)alloc(64);
  int*    s_tok = (int*)alloc(NASSIGN * 4);
  float*  s_wgt = (float*)alloc(NASSIGN * 4);
  bf16*   zpadb = (bf16*)alloc((HID + 64) * 2);
  bf16*   xb    = (bf16*)alloc((size_t)NTOK * HID * 2);
  bf16*   w1b   = (bf16*)alloc((size_t)NEXP * 2 * IMOE * HID * 2);
  bf16*   w2b   = (bf16*)alloc((size_t)NEXP * HID * IMOE * 2);
  bf16*   sgub  = (bf16*)alloc((size_t)2 * ISH * HID * 2);
  bf16*   sdwb  = (bf16*)alloc((size_t)HID * ISH * 2);
  bf16*   h_sh  = (bf16*)alloc((size_t)NTOK * ISH * 2);
  bf16*   h_e   = (bf16*)alloc((size_t)(NASSIGN + 128) * IMOE * 2);  // pad tail rows (BM=128)

  hipMemsetAsync(zpadb, 0, (HID + 64) * 2, stream);
  hipMemsetAsync(d_out, 0, (size_t)out_size * 4, stream);
  router_kernel<<<NTOK, 256, 0, stream>>>(x, gw, sgw, sg, tki, tkw);
  scatter_kernel<<<1, 256, 0, stream>>>(tki, tkw, offs, s_tok, s_wgt);
  convert_kernel<<<CVT_BLOCKS, 256, 0, stream>>>(x, w1, w2, sguw, sdw,
                                                 xb, w1b, w2b, sgub, sdwb);

  // shared gate_up -> h_sh [1024, 5632]
  gemm_gu<128, false><<<dim3(ISH / 64, NTOK / 128, 1), 256, 0, stream>>>(
      xb, sgub, 0, (long)ISH * HID, h_sh, ISH, nullptr, nullptr, zpadb);
  // expert gate_up (grouped, BM=128; gridY=16 covers all 2048 assigns) -> h_e
  gemm_gu<128, true><<<dim3(IMOE / 64, 16, NEXP), 256, 0, stream>>>(
      xb, w1b, (long)2 * IMOE * HID, (long)IMOE * HID, h_e, IMOE, offs, s_tok, zpadb);
  // shared down (split-K=8): out += sg[t] * h_sh . sdw^T
  gemm_down<128, false, 8><<<dim3(HID / 128, NTOK / 128, 8), 256, 0, stream>>>(
      h_sh, ISH, sdwb, 0, out, sg, nullptr, nullptr);
  // expert down (grouped, BM=128, split-K=2): out[token] += wgt * h_e . w2[e]^T
  gemm_down<128, true, 2><<<dim3(HID / 128, 16, NEXP * 2), 256, 0, stream>>>(
      h_e, IMOE, w2b, (long)HID * IMOE, out, s_wgt, offs, s_tok);
}

// Round 2
// 673.656 us; speedup vs baseline: 1.0872x; 1.0703x over previous
//
#include <hip/hip_runtime.h>
#include <hip/hip_bf16.h>
#include <math.h>

// Problem constants
#define HID   2048
#define NEXP  8
#define IMOE  1408
#define ISH   5632
#define NTOK  1024
#define NASSIGN 2048   // NTOK * TOP_K

typedef __bf16 bf16;
typedef __bf16 bf16x4 __attribute__((ext_vector_type(4)));
typedef __bf16 bf16x8 __attribute__((ext_vector_type(8)));
typedef float  f32x4  __attribute__((ext_vector_type(4)));

// async 16B/lane global->LDS. lptr must be wave-uniform; HW adds lane*16.
__device__ inline void async16(const bf16* g, bf16* l) {
  __builtin_amdgcn_global_load_lds(
      (const __attribute__((address_space(1))) void*)g,
      (__attribute__((address_space(3))) void*)l, 16, 0, 0);
}

// ---------------------------------------------------------------------------
// fp32 -> bf16 conversion, single streaming pass.
// Fully-coalesced loads: lane l reads float4 at seg+16*l (1KB/instr/wave),
// stores bf16x4 at 8*l (512B/instr/wave). 8192-elem chunks, 8 sub-iters for
// ILP. Segment select is block-uniform (chunk granularity divides segments).
// Segment boundaries in 8192-elem chunks:
//   x 256 | w1 5632 | w2 2816 | sgu 2816 | sdw 1408   (total 12928)
// ---------------------------------------------------------------------------
#define CC0 256L
#define CC1 5888L
#define CC2 8704L
#define CC3 11520L
#define CC4 12928L     // total 8192-elem chunks
#define CVT_BLOCKS 2048

__global__ __launch_bounds__(256) void convert_kernel(
    const float* __restrict__ x, const float* __restrict__ w1,
    const float* __restrict__ w2, const float* __restrict__ sgu,
    const float* __restrict__ sdw,
    bf16* __restrict__ xb, bf16* __restrict__ w1b, bf16* __restrict__ w2b,
    bf16* __restrict__ sgub, bf16* __restrict__ sdwb)
{
  const int tid = threadIdx.x;
  for (long c = blockIdx.x; c < CC4; c += CVT_BLOCKS) {
    const float* s; bf16* d; long off;
    if      (c < CC0) { s = x;   d = xb;   off = c; }
    else if (c < CC1) { s = w1;  d = w1b;  off = c - CC0; }
    else if (c < CC2) { s = w2;  d = w2b;  off = c - CC1; }
    else if (c < CC3) { s = sgu; d = sgub; off = c - CC2; }
    else              { s = sdw; d = sdwb; off = c - CC3; }
    long base = off * 8192 + (long)tid * 4;
    f32x4 v[8];
#pragma unroll
    for (int sub = 0; sub < 8; sub++)
      v[sub] = __builtin_nontemporal_load((const f32x4*)(s + base + sub * 1024));
#pragma unroll
    for (int sub = 0; sub < 8; sub++) {
      bf16x4 r;
      r[0] = (bf16)v[sub][0]; r[1] = (bf16)v[sub][1];
      r[2] = (bf16)v[sub][2]; r[3] = (bf16)v[sub][3];
      *(bf16x4*)(d + base + sub * 1024) = r;
    }
  }
}

// ---------------------------------------------------------------------------
// Router (fp32): top-2 renormalized = sigmoid(l0-l1); shared sigmoid gate.
// ---------------------------------------------------------------------------
__global__ __launch_bounds__(256) void router_kernel(
    const float* __restrict__ x, const float* __restrict__ gate_w,
    const float* __restrict__ sgate_w, float* __restrict__ sg,
    int2* __restrict__ tk_idx, float2* __restrict__ tk_w)
{
  const int t = blockIdx.x;
  const float* xr = x + (long)t * HID;
  float p[9];
#pragma unroll
  for (int i = 0; i < 9; i++) p[i] = 0.f;
  for (int c = threadIdx.x; c < HID; c += 256) {
    float xv = xr[c];
#pragma unroll
    for (int e = 0; e < 8; e++) p[e] += xv * gate_w[e * HID + c];
    p[8] += xv * sgate_w[c];
  }
#pragma unroll
  for (int i = 0; i < 9; i++)
    for (int off = 32; off > 0; off >>= 1)
      p[i] += __shfl_xor(p[i], off, 64);
  __shared__ float red[4][9];
  const int wave = threadIdx.x >> 6, lane = threadIdx.x & 63;
  if (lane == 0)
    for (int i = 0; i < 9; i++) red[wave][i] = p[i];
  __syncthreads();
  if (threadIdx.x == 0) {
    float l[9];
    for (int i = 0; i < 9; i++)
      l[i] = red[0][i] + red[1][i] + red[2][i] + red[3][i];
    int i0 = 0;
    for (int e = 1; e < 8; e++) if (l[e] > l[i0]) i0 = e;
    int i1 = -1;
    for (int e = 0; e < 8; e++) {
      if (e == i0) continue;
      if (i1 < 0 || l[e] > l[i1]) i1 = e;
    }
    float w0 = 1.f / (1.f + __expf(l[i1] - l[i0]));
    tk_idx[t] = make_int2(i0, i1);
    tk_w[t]   = make_float2(w0, 1.f - w0);
    sg[t]     = 1.f / (1.f + __expf(-l[8]));
  }
}

__global__ __launch_bounds__(256) void scatter_kernel(
    const int2* __restrict__ tk_idx, const float2* __restrict__ tk_w,
    int* __restrict__ offs, int* __restrict__ s_tok, float* __restrict__ s_wgt)
{
  __shared__ int cnt[8], pos[8];
  if (threadIdx.x < 8) cnt[threadIdx.x] = 0;
  __syncthreads();
  for (int a = threadIdx.x; a < NASSIGN; a += 256) {
    int2 ii = tk_idx[a >> 1];
    int e = (a & 1) ? ii.y : ii.x;
    atomicAdd(&cnt[e], 1);
  }
  __syncthreads();
  if (threadIdx.x == 0) {
    int s = 0;
    for (int e = 0; e < 8; e++) { offs[e] = s; pos[e] = s; s += cnt[e]; }
    offs[8] = s;
  }
  __syncthreads();
  for (int a = threadIdx.x; a < NASSIGN; a += 256) {
    int t = a >> 1;
    int2 ii = tk_idx[t];
    float2 ww = tk_w[t];
    int   e = (a & 1) ? ii.y : ii.x;
    float w = (a & 1) ? ww.y : ww.x;
    int pp = atomicAdd(&pos[e], 1);
    s_tok[pp] = t;
    s_wgt[pp] = w;
  }
}

// ---------------------------------------------------------------------------
// Fused gate_up GEMM + SiLU*mul (m97-style): bf16 global_load_lds width=16,
// single LDS buffer, 2 barriers/step, BK=32, 16x16x32 MFMA.
// LDS tiles unpadded [rows][32] bf16; 16B chunks XOR-swizzled by (row&3)
// on the GLOBAL side so frag ds_read_b128 is conflict-free.
// B tile = 128 rows: [0..63]=gate, [64..127]=up for 64 output h-cols.
// ---------------------------------------------------------------------------
template<int BM, bool GROUPED>
__global__ __launch_bounds__(256) void gemm_gu(
    const bf16* __restrict__ X,
    const bf16* __restrict__ Wg_base, long expert_stride, long up_off,
    bf16* __restrict__ Hout, int hstride,
    const int* __restrict__ offs, const int* __restrict__ s_tok,
    const bf16* __restrict__ zpad)
{
  static_assert(BM == 64 || BM == 128, "BM");
  constexpr int K = HID, NS = K / 32;
  constexpr int AIP = BM / 64;   // A staging insts per wave
  constexpr int AF  = BM / 32;   // A frags per wave
  const int n0 = blockIdx.x * 64;
  const int e  = GROUPED ? blockIdx.z : 0;
  int m_base, m_end;
  if (GROUPED) {
    m_base = offs[e] + blockIdx.y * BM;
    m_end  = offs[e + 1];
    if (m_base >= m_end) return;
  } else { m_base = blockIdx.y * BM; m_end = NTOK; }
  const bf16* Wg = Wg_base + (long)e * expert_stride;

  __shared__ __attribute__((aligned(16))) bf16 As[BM * 32];
  __shared__ __attribute__((aligned(16))) bf16 Bs[128 * 32];

  const int tid = threadIdx.x, wave = tid >> 6, lane = tid & 63;

  // staging pointers: inst covers 16 rows; lane -> (row=l>>2, pos=l&3),
  // fetch global chunk g = pos ^ (row&3)  (swizzle)
  const bf16* pa[AIP]; bf16* la[AIP];
#pragma unroll
  for (int q = 0; q < AIP; q++) {
    int ia  = wave * AIP + q;
    int rl  = ia * 16 + (lane >> 2);
    int gch = (lane & 3) ^ (rl & 3);
    const bf16* src;
    if (GROUPED) {
      int gr  = m_base + rl;
      int tok = (gr < m_end) ? s_tok[gr] : -1;
      src = (tok >= 0) ? X + (long)tok * K : zpad;
    } else src = X + (long)(m_base + rl) * K;
    pa[q] = src + gch * 8;
    la[q] = As + ia * 512;
  }
  const bf16* pb[2]; bf16* lb[2];
#pragma unroll
  for (int q = 0; q < 2; q++) {
    int ib  = wave * 2 + q;
    int rl  = ib * 16 + (lane >> 2);
    int gch = (lane & 3) ^ (rl & 3);
    const bf16* src = (rl < 64) ? Wg + (long)(n0 + rl) * K
                                : Wg + up_off + (long)(n0 + rl - 64) * K;
    pb[q] = src + gch * 8;
    lb[q] = Bs + ib * 512;
  }

  const int wm = wave >> 1, wn = wave & 1;
  f32x4 accg[AF][2], accu[AF][2];
#pragma unroll
  for (int i = 0; i < AF; i++)
#pragma unroll
    for (int j = 0; j < 2; j++) {
      accg[i][j] = f32x4{0.f, 0.f, 0.f, 0.f};
      accu[i][j] = f32x4{0.f, 0.f, 0.f, 0.f};
    }

  const int fr = lane & 15, cch = lane >> 4;   // frag row, k-chunk

  for (int s = 0; s < NS; s++) {
    __syncthreads();            // previous consumers done with LDS
#pragma unroll
    for (int q = 0; q < AIP; q++) { async16(pa[q], la[q]); pa[q] += 32; }
#pragma unroll
    for (int q = 0; q < 2;   q++) { async16(pb[q], lb[q]); pb[q] += 32; }
    asm volatile("s_waitcnt vmcnt(0)" ::: "memory");
    __syncthreads();            // staged tile visible to all waves

    bf16x8 a[AF], bg[2], bu[2];
#pragma unroll
    for (int i = 0; i < AF; i++) {
      int ar = wm * (AF * 16) + i * 16 + fr;
      a[i] = *(const bf16x8*)&As[ar * 32 + ((cch ^ (ar & 3)) * 8)];
    }
#pragma unroll
    for (int j = 0; j < 2; j++) {
      int br = wn * 32 + j * 16 + fr;
      int ur = 64 + br;
      bg[j] = *(const bf16x8*)&Bs[br * 32 + ((cch ^ (br & 3)) * 8)];
      bu[j] = *(const bf16x8*)&Bs[ur * 32 + ((cch ^ (ur & 3)) * 8)];
    }
#pragma unroll
    for (int i = 0; i < AF; i++)
#pragma unroll
      for (int j = 0; j < 2; j++) {
        accg[i][j] = __builtin_amdgcn_mfma_f32_16x16x32_bf16(a[i], bg[j], accg[i][j], 0, 0, 0);
        accu[i][j] = __builtin_amdgcn_mfma_f32_16x16x32_bf16(a[i], bu[j], accu[i][j], 0, 0, 0);
      }
  }
  // epilogue: h = silu(g)*u  (C/D: row=(lane>>4)*4+r, col=lane&15)
#pragma unroll
  for (int i = 0; i < AF; i++)
#pragma unroll
    for (int j = 0; j < 2; j++)
#pragma unroll
      for (int r = 0; r < 4; r++) {
        int row  = wm * (AF * 16) + i * 16 + (lane >> 4) * 4 + r;
        int grow = m_base + row;
        if (GROUPED && grow >= m_end) continue;
        int col = wn * 32 + j * 16 + (lane & 15);
        float g = accg[i][j][r], u = accu[i][j][r];
        float h = g / (1.f + __expf(-g)) * u;
        Hout[(long)grow * hstride + n0 + col] = (bf16)h;
      }
}

// ---------------------------------------------------------------------------
// Down GEMM: out[target(m), n] += scale(m) * (H . W^T)[m,n]
// Same m97 staging. BM x 128 tile. atomicAdd fp32 epilogue.
// GROUPED: blockIdx.z = e*KSPLIT + ks.   !GROUPED: blockIdx.z = ks.
// ---------------------------------------------------------------------------
template<int BM, bool GROUPED, int KSPLIT>
__global__ __launch_bounds__(256) void gemm_down(
    const bf16* __restrict__ Hin, int K,
    const bf16* __restrict__ W_base, long expert_stride,
    float* __restrict__ Out, const float* __restrict__ scale,
    const int* __restrict__ offs, const int* __restrict__ s_tok)
{
  static_assert(BM == 64 || BM == 128, "BM");
  constexpr int AIP = BM / 64, AF = BM / 32;
  const int n0 = blockIdx.x * 128;
  int e = 0, ks, m_base, m_end;
  if (GROUPED) {
    e  = blockIdx.z / KSPLIT;
    ks = blockIdx.z % KSPLIT;
    m_base = offs[e] + blockIdx.y * BM;
    m_end  = offs[e + 1];
    if (m_base >= m_end) return;
  } else {
    ks = blockIdx.z;
    m_base = blockIdx.y * BM;
    m_end  = NTOK;
  }
  const int k_lo = ks * (K / KSPLIT);
  const int NS   = (K / KSPLIT) / 32;
  const bf16* W = W_base + (long)e * expert_stride;

  __shared__ __attribute__((aligned(16))) bf16 As[BM * 32];
  __shared__ __attribute__((aligned(16))) bf16 Bs[128 * 32];

  const int tid = threadIdx.x, wave = tid >> 6, lane = tid & 63;

  const bf16* pa[AIP]; bf16* la[AIP];
#pragma unroll
  for (int q = 0; q < AIP; q++) {
    int ia  = wave * AIP + q;
    int rl  = ia * 16 + (lane >> 2);
    int gch = (lane & 3) ^ (rl & 3);
    pa[q] = Hin + (long)(m_base + rl) * K + k_lo + gch * 8;  // rows compact; tail pad ok
    la[q] = As + ia * 512;
  }
  const bf16* pb[2]; bf16* lb[2];
#pragma unroll
  for (int q = 0; q < 2; q++) {
    int ib  = wave * 2 + q;
    int rl  = ib * 16 + (lane >> 2);
    int gch = (lane & 3) ^ (rl & 3);
    pb[q] = W + (long)(n0 + rl) * K + k_lo + gch * 8;
    lb[q] = Bs + ib * 512;
  }

  const int wm = wave >> 1, wn = wave & 1;
  f32x4 acc[AF][4];
#pragma unroll
  for (int i = 0; i < AF; i++)
#pragma unroll
    for (int j = 0; j < 4; j++) acc[i][j] = f32x4{0.f, 0.f, 0.f, 0.f};

  const int fr = lane & 15, cch = lane >> 4;

  for (int s = 0; s < NS; s++) {
    __syncthreads();
#pragma unroll
    for (int q = 0; q < AIP; q++) { async16(pa[q], la[q]); pa[q] += 32; }
#pragma unroll
    for (int q = 0; q < 2;   q++) { async16(pb[q], lb[q]); pb[q] += 32; }
    asm volatile("s_waitcnt vmcnt(0)" ::: "memory");
    __syncthreads();

    bf16x8 a[AF], b[4];
#pragma unroll
    for (int i = 0; i < AF; i++) {
      int ar = wm * (AF * 16) + i * 16 + fr;
      a[i] = *(const bf16x8*)&As[ar * 32 + ((cch ^ (ar & 3)) * 8)];
    }
#pragma unroll
    for (int j = 0; j < 4; j++) {
      int br = wn * 64 + j * 16 + fr;
      b[j] = *(const bf16x8*)&Bs[br * 32 + ((cch ^ (br & 3)) * 8)];
    }
#pragma unroll
    for (int i = 0; i < AF; i++)
#pragma unroll
      for (int j = 0; j < 4; j++)
        acc[i][j] = __builtin_amdgcn_mfma_f32_16x16x32_bf16(a[i], b[j], acc[i][j], 0, 0, 0);
  }
#pragma unroll
  for (int i = 0; i < AF; i++)
#pragma unroll
    for (int j = 0; j < 4; j++)
#pragma unroll
      for (int r = 0; r < 4; r++) {
        int row  = wm * (AF * 16) + i * 16 + (lane >> 4) * 4 + r;
        int grow = m_base + row;
        if (GROUPED && grow >= m_end) continue;
        int col = wn * 64 + j * 16 + (lane & 15);
        float sc = scale[grow];
        int target = GROUPED ? s_tok[grow] : grow;
        atomicAdd(&Out[(long)target * HID + n0 + col], sc * acc[i][j][r]);
      }
}

// ---------------------------------------------------------------------------
extern "C" void kernel_launch(void* const* d_in, const int* in_sizes, int n_in,
                              void* d_out, int out_size, void* d_ws, size_t ws_size,
                              hipStream_t stream)
{
  const float* x    = (const float*)d_in[0];
  const float* gw   = (const float*)d_in[1];
  const float* w1   = (const float*)d_in[2];
  const float* w2   = (const float*)d_in[3];
  const float* sguw = (const float*)d_in[4];
  const float* sdw  = (const float*)d_in[5];
  const float* sgw  = (const float*)d_in[6];
  float* out = (float*)d_out;

  char* ws = (char*)d_ws;
  size_t off = 0;
  auto alloc = [&](size_t bytes) {
    void* p = ws + off;
    off = (off + bytes + 255) & ~(size_t)255;
    return p;
  };
  float*  sg    = (float*)alloc(NTOK * 4);
  int2*   tki   = (int2*)alloc(NTOK * 8);
  float2* tkw   = (float2*)alloc(NTOK * 8);
  int*    offs  = (int*)alloc(64);
  int*    s_tok = (int*)alloc(NASSIGN * 4);
  float*  s_wgt = (float*)alloc(NASSIGN * 4);
  bf16*   zpadb = (bf16*)alloc((HID + 64) * 2);
  bf16*   xb    = (bf16*)alloc((size_t)NTOK * HID * 2);
  bf16*   w1b   = (bf16*)alloc((size_t)NEXP * 2 * IMOE * HID * 2);
  bf16*   w2b   = (bf16*)alloc((size_t)NEXP * HID * IMOE * 2);
  bf16*   sgub  = (bf16*)alloc((size_t)2 * ISH * HID * 2);
  bf16*   sdwb  = (bf16*)alloc((size_t)HID * ISH * 2);
  bf16*   h_sh  = (bf16*)alloc((size_t)NTOK * ISH * 2);
  bf16*   h_e   = (bf16*)alloc((size_t)(NASSIGN + 128) * IMOE * 2);  // pad tail rows (BM=128)

  hipMemsetAsync(zpadb, 0, (HID + 64) * 2, stream);
  hipMemsetAsync(d_out, 0, (size_t)out_size * 4, stream);
  router_kernel<<<NTOK, 256, 0, stream>>>(x, gw, sgw, sg, tki, tkw);
  scatter_kernel<<<1, 256, 0, stream>>>(tki, tkw, offs, s_tok, s_wgt);
  convert_kernel<<<CVT_BLOCKS, 256, 0, stream>>>(x, w1, w2, sguw, sdw,
                                                 xb, w1b, w2b, sgub, sdwb);

  // shared gate_up -> h_sh [1024, 5632]
  gemm_gu<128, false><<<dim3(ISH / 64, NTOK / 128, 1), 256, 0, stream>>>(
      xb, sgub, 0, (long)ISH * HID, h_sh, ISH, nullptr, nullptr, zpadb);
  // expert gate_up (grouped, BM=128; gridY=16 covers all 2048 assigns) -> h_e
  gemm_gu<128, true><<<dim3(IMOE / 64, 16, NEXP), 256, 0, stream>>>(
      xb, w1b, (long)2 * IMOE * HID, (long)IMOE * HID, h_e, IMOE, offs, s_tok, zpadb);
  // shared down (split-K=8): out += sg[t] * h_sh . sdw^T
  gemm_down<128, false, 8><<<dim3(HID / 128, NTOK / 128, 8), 256, 0, stream>>>(
      h_sh, ISH, sdwb, 0, out, sg, nullptr, nullptr);
  // expert down (grouped, BM=128, split-K=2): out[token] += wgt * h_e . w2[e]^T
  gemm_down<128, true, 2><<<dim3(HID / 128, 16, NEXP * 2), 256, 0, stream>>>(
      h_e, IMOE, w2b, (long)HID * IMOE, out, s_wgt, offs, s_tok);
}

// Round 3
// 643.072 us; speedup vs baseline: 1.1389x; 1.0476x over previous
//
#include <hip/hip_runtime.h>
#include <hip/hip_bf16.h>
#include <math.h>

// Problem constants
#define HID   2048
#define NEXP  8
#define IMOE  1408
#define ISH   5632
#define NTOK  1024
#define NASSIGN 2048   // NTOK * TOP_K

typedef __bf16 bf16;
typedef __bf16 bf16x4 __attribute__((ext_vector_type(4)));
typedef __bf16 bf16x8 __attribute__((ext_vector_type(8)));
typedef float  f32x4  __attribute__((ext_vector_type(4)));

// async 16B/lane global->LDS. lptr must be wave-uniform; HW adds lane*16.
__device__ inline void async16(const bf16* g, bf16* l) {
  __builtin_amdgcn_global_load_lds(
      (const __attribute__((address_space(1))) void*)g,
      (__attribute__((address_space(3))) void*)l, 16, 0, 0);
}

// 2D-chunked XCD swizzle: 8-block chunks (4 x-panels × 2 y-panels) whose
// members share one XCD (consecutive bids round-robin XCDs, so chunk members
// use bids ≡ xcd (mod 8)). Bijective when NB % 64 == 0.
// s -> (bx, by):  p = (s>>3)&7 (pos in chunk), c = (s&7) + 8*(s>>6) (chunk id)
__device__ inline void swz_decode(int s, int cxn, int& bx, int& by) {
  int p  = (s >> 3) & 7;
  int c  = (s & 7) + ((s >> 6) << 3);
  int cx = c % cxn, cy = c / cxn;
  bx = cx * 4 + (p & 3);
  by = cy * 2 + (p >> 2);
}

// ---------------------------------------------------------------------------
// fp32 -> bf16 conversion, single streaming pass, fully-coalesced loads.
// ---------------------------------------------------------------------------
#define CC0 256L
#define CC1 5888L
#define CC2 8704L
#define CC3 11520L
#define CC4 12928L     // total 8192-elem chunks
#define CVT_BLOCKS 2048

__global__ __launch_bounds__(256) void convert_kernel(
    const float* __restrict__ x, const float* __restrict__ w1,
    const float* __restrict__ w2, const float* __restrict__ sgu,
    const float* __restrict__ sdw,
    bf16* __restrict__ xb, bf16* __restrict__ w1b, bf16* __restrict__ w2b,
    bf16* __restrict__ sgub, bf16* __restrict__ sdwb)
{
  const int tid = threadIdx.x;
  for (long c = blockIdx.x; c < CC4; c += CVT_BLOCKS) {
    const float* s; bf16* d; long off;
    if      (c < CC0) { s = x;   d = xb;   off = c; }
    else if (c < CC1) { s = w1;  d = w1b;  off = c - CC0; }
    else if (c < CC2) { s = w2;  d = w2b;  off = c - CC1; }
    else if (c < CC3) { s = sgu; d = sgub; off = c - CC2; }
    else              { s = sdw; d = sdwb; off = c - CC3; }
    long base = off * 8192 + (long)tid * 4;
    f32x4 v[8];
#pragma unroll
    for (int sub = 0; sub < 8; sub++)
      v[sub] = __builtin_nontemporal_load((const f32x4*)(s + base + sub * 1024));
#pragma unroll
    for (int sub = 0; sub < 8; sub++) {
      bf16x4 r;
      r[0] = (bf16)v[sub][0]; r[1] = (bf16)v[sub][1];
      r[2] = (bf16)v[sub][2]; r[3] = (bf16)v[sub][3];
      *(bf16x4*)(d + base + sub * 1024) = r;
    }
  }
}

// ---------------------------------------------------------------------------
// Router (fp32): top-2 renormalized = sigmoid(l0-l1); shared sigmoid gate.
// ---------------------------------------------------------------------------
__global__ __launch_bounds__(256) void router_kernel(
    const float* __restrict__ x, const float* __restrict__ gate_w,
    const float* __restrict__ sgate_w, float* __restrict__ sg,
    int2* __restrict__ tk_idx, float2* __restrict__ tk_w)
{
  const int t = blockIdx.x;
  const float* xr = x + (long)t * HID;
  float p[9];
#pragma unroll
  for (int i = 0; i < 9; i++) p[i] = 0.f;
  for (int c = threadIdx.x; c < HID; c += 256) {
    float xv = xr[c];
#pragma unroll
    for (int e = 0; e < 8; e++) p[e] += xv * gate_w[e * HID + c];
    p[8] += xv * sgate_w[c];
  }
#pragma unroll
  for (int i = 0; i < 9; i++)
    for (int off = 32; off > 0; off >>= 1)
      p[i] += __shfl_xor(p[i], off, 64);
  __shared__ float red[4][9];
  const int wave = threadIdx.x >> 6, lane = threadIdx.x & 63;
  if (lane == 0)
    for (int i = 0; i < 9; i++) red[wave][i] = p[i];
  __syncthreads();
  if (threadIdx.x == 0) {
    float l[9];
    for (int i = 0; i < 9; i++)
      l[i] = red[0][i] + red[1][i] + red[2][i] + red[3][i];
    int i0 = 0;
    for (int e = 1; e < 8; e++) if (l[e] > l[i0]) i0 = e;
    int i1 = -1;
    for (int e = 0; e < 8; e++) {
      if (e == i0) continue;
      if (i1 < 0 || l[e] > l[i1]) i1 = e;
    }
    float w0 = 1.f / (1.f + __expf(l[i1] - l[i0]));
    tk_idx[t] = make_int2(i0, i1);
    tk_w[t]   = make_float2(w0, 1.f - w0);
    sg[t]     = 1.f / (1.f + __expf(-l[8]));
  }
}

__global__ __launch_bounds__(256) void scatter_kernel(
    const int2* __restrict__ tk_idx, const float2* __restrict__ tk_w,
    int* __restrict__ offs, int* __restrict__ s_tok, float* __restrict__ s_wgt)
{
  __shared__ int cnt[8], pos[8];
  if (threadIdx.x < 8) cnt[threadIdx.x] = 0;
  __syncthreads();
  for (int a = threadIdx.x; a < NASSIGN; a += 256) {
    int2 ii = tk_idx[a >> 1];
    int e = (a & 1) ? ii.y : ii.x;
    atomicAdd(&cnt[e], 1);
  }
  __syncthreads();
  if (threadIdx.x == 0) {
    int s = 0;
    for (int e = 0; e < 8; e++) { offs[e] = s; pos[e] = s; s += cnt[e]; }
    offs[8] = s;
  }
  __syncthreads();
  for (int a = threadIdx.x; a < NASSIGN; a += 256) {
    int t = a >> 1;
    int2 ii = tk_idx[t];
    float2 ww = tk_w[t];
    int   e = (a & 1) ? ii.y : ii.x;
    float w = (a & 1) ? ww.y : ww.x;
    int pp = atomicAdd(&pos[e], 1);
    s_tok[pp] = t;
    s_wgt[pp] = w;
  }
}

// ---------------------------------------------------------------------------
// gate_up GEMM core (BM=128, BN=64 h-cols => 128 B rows g+u), m97-style:
// global_load_lds width=16, single LDS buffer, 2 barriers/step, BK=32,
// 16x16x32 MFMA. 16B chunks XOR-swizzled by (row&3) on the GLOBAL side so
// frag ds_read_b128 is conflict-free. grouped is block-uniform runtime.
// ---------------------------------------------------------------------------
__device__ __forceinline__ void gu_core(
    bf16* __restrict__ As, bf16* __restrict__ Bs,
    const bf16* __restrict__ X,
    const bf16* __restrict__ Wg, long up_off,
    bf16* __restrict__ Hout, int hstride,
    const int* __restrict__ s_tok, const bf16* __restrict__ zpad,
    bool grouped, int m_base, int m_end, int n0)
{
  constexpr int K = HID, NS = K / 32;
  const int tid = threadIdx.x, wave = tid >> 6, lane = tid & 63;

  const bf16* pa[2]; bf16* la[2];
#pragma unroll
  for (int q = 0; q < 2; q++) {
    int ia  = wave * 2 + q;
    int rl  = ia * 16 + (lane >> 2);
    int gch = (lane & 3) ^ (rl & 3);
    const bf16* src;
    if (grouped) {
      int gr  = m_base + rl;
      int tok = (gr < m_end) ? s_tok[gr] : -1;
      src = (tok >= 0) ? X + (long)tok * K : zpad;
    } else src = X + (long)(m_base + rl) * K;
    pa[q] = src + gch * 8;
    la[q] = As + ia * 512;
  }
  const bf16* pb[2]; bf16* lb[2];
#pragma unroll
  for (int q = 0; q < 2; q++) {
    int ib  = wave * 2 + q;
    int rl  = ib * 16 + (lane >> 2);
    int gch = (lane & 3) ^ (rl & 3);
    const bf16* src = (rl < 64) ? Wg + (long)(n0 + rl) * K
                                : Wg + up_off + (long)(n0 + rl - 64) * K;
    pb[q] = src + gch * 8;
    lb[q] = Bs + ib * 512;
  }

  const int wm = wave >> 1, wn = wave & 1;
  f32x4 accg[4][2], accu[4][2];
#pragma unroll
  for (int i = 0; i < 4; i++)
#pragma unroll
    for (int j = 0; j < 2; j++) {
      accg[i][j] = f32x4{0.f, 0.f, 0.f, 0.f};
      accu[i][j] = f32x4{0.f, 0.f, 0.f, 0.f};
    }

  const int fr = lane & 15, cch = lane >> 4;   // frag row, k-chunk

  for (int s = 0; s < NS; s++) {
    __syncthreads();
#pragma unroll
    for (int q = 0; q < 2; q++) { async16(pa[q], la[q]); pa[q] += 32; }
#pragma unroll
    for (int q = 0; q < 2; q++) { async16(pb[q], lb[q]); pb[q] += 32; }
    asm volatile("s_waitcnt vmcnt(0)" ::: "memory");
    __syncthreads();

    bf16x8 a[4], bg[2], bu[2];
#pragma unroll
    for (int i = 0; i < 4; i++) {
      int ar = wm * 64 + i * 16 + fr;
      a[i] = *(const bf16x8*)&As[ar * 32 + ((cch ^ (ar & 3)) * 8)];
    }
#pragma unroll
    for (int j = 0; j < 2; j++) {
      int br = wn * 32 + j * 16 + fr;
      int ur = 64 + br;
      bg[j] = *(const bf16x8*)&Bs[br * 32 + ((cch ^ (br & 3)) * 8)];
      bu[j] = *(const bf16x8*)&Bs[ur * 32 + ((cch ^ (ur & 3)) * 8)];
    }
#pragma unroll
    for (int i = 0; i < 4; i++)
#pragma unroll
      for (int j = 0; j < 2; j++) {
        accg[i][j] = __builtin_amdgcn_mfma_f32_16x16x32_bf16(a[i], bg[j], accg[i][j], 0, 0, 0);
        accu[i][j] = __builtin_amdgcn_mfma_f32_16x16x32_bf16(a[i], bu[j], accu[i][j], 0, 0, 0);
      }
  }
  // epilogue: h = silu(g)*u  (C/D: row=(lane>>4)*4+r, col=lane&15)
#pragma unroll
  for (int i = 0; i < 4; i++)
#pragma unroll
    for (int j = 0; j < 2; j++)
#pragma unroll
      for (int r = 0; r < 4; r++) {
        int row  = wm * 64 + i * 16 + (lane >> 4) * 4 + r;
        int grow = m_base + row;
        if (grow >= m_end) continue;
        int col = wn * 32 + j * 16 + (lane & 15);
        float g = accg[i][j][r], u = accu[i][j][r];
        float h = g / (1.f + __expf(-g)) * u;
        Hout[(long)grow * hstride + n0 + col] = (bf16)h;
      }
}

// Fused launch: [0, 704) shared gate_up (chunk-swizzled), then expert blocks.
#define GU_SH_BLOCKS 704                 // (ISH/64)=88 x, (NTOK/128)=8 y
#define GU_E_X 22                        // IMOE/64
#define GU_BLOCKS (GU_SH_BLOCKS + GU_E_X * 16 * NEXP)

__global__ __launch_bounds__(256) void gemm_gu_fused(
    const bf16* __restrict__ X,
    const bf16* __restrict__ sgu, const bf16* __restrict__ w1,
    bf16* __restrict__ Hsh, bf16* __restrict__ He,
    const int* __restrict__ offs, const int* __restrict__ s_tok,
    const bf16* __restrict__ zpad)
{
  __shared__ __attribute__((aligned(16))) bf16 As[128 * 32];
  __shared__ __attribute__((aligned(16))) bf16 Bs[128 * 32];
  const int bid = blockIdx.x;
  const bf16* Wg; long up_off; bf16* Hout; int hstride;
  int n0, m_base, m_end; bool grouped;
  if (bid < GU_SH_BLOCKS) {
    int bx, by; swz_decode(bid, 22, bx, by);   // 88x * 8y, chunks 4x*2y
    n0 = bx * 64; m_base = by * 128; m_end = NTOK;
    Wg = sgu; up_off = (long)ISH * HID;
    Hout = Hsh; hstride = ISH; grouped = false;
  } else {
    int r = bid - GU_SH_BLOCKS;
    int bx = r % GU_E_X; r /= GU_E_X;
    int by = r % 16; int e = r / 16;
    m_base = offs[e] + by * 128; m_end = offs[e + 1];
    if (m_base >= m_end) return;
    n0 = bx * 64;
    Wg = w1 + (long)e * (2L * IMOE * HID); up_off = (long)IMOE * HID;
    Hout = He; hstride = IMOE; grouped = true;
  }
  gu_core(As, Bs, X, Wg, up_off, Hout, hstride, s_tok, zpad,
          grouped, m_base, m_end, n0);
}

// ---------------------------------------------------------------------------
// Down GEMM core: out[target(m), n] += scale(m) * (H . W^T)[m,n]
// BM=128 x BN=128 tile, runtime K / k_lo / NS. atomicAdd fp32 epilogue.
// ---------------------------------------------------------------------------
__device__ __forceinline__ void down_core(
    bf16* __restrict__ As, bf16* __restrict__ Bs,
    const bf16* __restrict__ Hin, int K, int k_lo, int NS,
    const bf16* __restrict__ W,
    float* __restrict__ Out, const float* __restrict__ scale,
    const int* __restrict__ s_tok, bool grouped,
    int m_base, int m_end, int n0)
{
  const int tid = threadIdx.x, wave = tid >> 6, lane = tid & 63;

  const bf16* pa[2]; bf16* la[2];
#pragma unroll
  for (int q = 0; q < 2; q++) {
    int ia  = wave * 2 + q;
    int rl  = ia * 16 + (lane >> 2);
    int gch = (lane & 3) ^ (rl & 3);
    pa[q] = Hin + (long)(m_base + rl) * K + k_lo + gch * 8;  // rows compact; tail pad ok
    la[q] = As + ia * 512;
  }
  const bf16* pb[2]; bf16* lb[2];
#pragma unroll
  for (int q = 0; q < 2; q++) {
    int ib  = wave * 2 + q;
    int rl  = ib * 16 + (lane >> 2);
    int gch = (lane & 3) ^ (rl & 3);
    pb[q] = W + (long)(n0 + rl) * K + k_lo + gch * 8;
    lb[q] = Bs + ib * 512;
  }

  const int wm = wave >> 1, wn = wave & 1;
  f32x4 acc[4][4];
#pragma unroll
  for (int i = 0; i < 4; i++)
#pragma unroll
    for (int j = 0; j < 4; j++) acc[i][j] = f32x4{0.f, 0.f, 0.f, 0.f};

  const int fr = lane & 15, cch = lane >> 4;

  for (int s = 0; s < NS; s++) {
    __syncthreads();
#pragma unroll
    for (int q = 0; q < 2; q++) { async16(pa[q], la[q]); pa[q] += 32; }
#pragma unroll
    for (int q = 0; q < 2; q++) { async16(pb[q], lb[q]); pb[q] += 32; }
    asm volatile("s_waitcnt vmcnt(0)" ::: "memory");
    __syncthreads();

    bf16x8 a[4], b[4];
#pragma unroll
    for (int i = 0; i < 4; i++) {
      int ar = wm * 64 + i * 16 + fr;
      a[i] = *(const bf16x8*)&As[ar * 32 + ((cch ^ (ar & 3)) * 8)];
    }
#pragma unroll
    for (int j = 0; j < 4; j++) {
      int br = wn * 64 + j * 16 + fr;
      b[j] = *(const bf16x8*)&Bs[br * 32 + ((cch ^ (br & 3)) * 8)];
    }
#pragma unroll
    for (int i = 0; i < 4; i++)
#pragma unroll
      for (int j = 0; j < 4; j++)
        acc[i][j] = __builtin_amdgcn_mfma_f32_16x16x32_bf16(a[i], b[j], acc[i][j], 0, 0, 0);
  }
#pragma unroll
  for (int i = 0; i < 4; i++)
#pragma unroll
    for (int j = 0; j < 4; j++)
#pragma unroll
      for (int r = 0; r < 4; r++) {
        int row  = wm * 64 + i * 16 + (lane >> 4) * 4 + r;
        int grow = m_base + row;
        if (grow >= m_end) continue;
        int col = wn * 64 + j * 16 + (lane & 15);
        float sc = scale[grow];
        int target = grouped ? s_tok[grow] : grow;
        atomicAdd(&Out[(long)target * HID + n0 + col], sc * acc[i][j][r]);
      }
}

// Fused launch: [0, 512) shared down (KSPLIT=4, chunk-swizzled per ks-plane),
// then expert down (KSPLIT=2).
#define DN_SH_BLOCKS 512                 // 16x * 8y * 4ks
#define DN_BLOCKS (DN_SH_BLOCKS + 16 * 16 * NEXP * 2)

__global__ __launch_bounds__(256) void gemm_down_fused(
    const bf16* __restrict__ Hsh, const bf16* __restrict__ He,
    const bf16* __restrict__ sdw, const bf16* __restrict__ w2,
    float* __restrict__ Out, const float* __restrict__ sg,
    const float* __restrict__ s_wgt,
    const int* __restrict__ offs, const int* __restrict__ s_tok)
{
  __shared__ __attribute__((aligned(16))) bf16 As[128 * 32];
  __shared__ __attribute__((aligned(16))) bf16 Bs[128 * 32];
  const int bid = blockIdx.x;
  const bf16* Hin; const bf16* W; const float* scale;
  int K, k_lo, NS, m_base, m_end, n0; bool grouped;
  if (bid < DN_SH_BLOCKS) {
    int plane = bid >> 7;                 // ks 0..3
    int bx, by; swz_decode(bid & 127, 4, bx, by);  // 16x * 8y, chunks 4x*2y
    Hin = Hsh; K = ISH; k_lo = plane * (ISH / 4); NS = (ISH / 4) / 32;  // 44
    W = sdw; scale = sg; grouped = false;
    m_base = by * 128; m_end = NTOK; n0 = bx * 128;
  } else {
    int r = bid - DN_SH_BLOCKS;
    int bx = r % 16; r /= 16;
    int by = r % 16; r /= 16;
    int e = r >> 1, ks = r & 1;
    m_base = offs[e] + by * 128; m_end = offs[e + 1];
    if (m_base >= m_end) return;
    Hin = He; K = IMOE; k_lo = ks * (IMOE / 2); NS = (IMOE / 2) / 32;   // 22
    W = w2 + (long)e * HID * IMOE; scale = s_wgt; grouped = true;
    n0 = bx * 128;
  }
  down_core(As, Bs, Hin, K, k_lo, NS, W, Out, scale, s_tok, grouped,
            m_base, m_end, n0);
}

// ---------------------------------------------------------------------------
extern "C" void kernel_launch(void* const* d_in, const int* in_sizes, int n_in,
                              void* d_out, int out_size, void* d_ws, size_t ws_size,
                              hipStream_t stream)
{
  const float* x    = (const float*)d_in[0];
  const float* gw   = (const float*)d_in[1];
  const float* w1   = (const float*)d_in[2];
  const float* w2   = (const float*)d_in[3];
  const float* sguw = (const float*)d_in[4];
  const float* sdw  = (const float*)d_in[5];
  const float* sgw  = (const float*)d_in[6];
  float* out = (float*)d_out;

  char* ws = (char*)d_ws;
  size_t off = 0;
  auto alloc = [&](size_t bytes) {
    void* p = ws + off;
    off = (off + bytes + 255) & ~(size_t)255;
    return p;
  };
  float*  sg    = (float*)alloc(NTOK * 4);
  int2*   tki   = (int2*)alloc(NTOK * 8);
  float2* tkw   = (float2*)alloc(NTOK * 8);
  int*    offs  = (int*)alloc(64);
  int*    s_tok = (int*)alloc(NASSIGN * 4);
  float*  s_wgt = (float*)alloc(NASSIGN * 4);
  bf16*   zpadb = (bf16*)alloc((HID + 64) * 2);
  bf16*   xb    = (bf16*)alloc((size_t)NTOK * HID * 2);
  bf16*   w1b   = (bf16*)alloc((size_t)NEXP * 2 * IMOE * HID * 2);
  bf16*   w2b   = (bf16*)alloc((size_t)NEXP * HID * IMOE * 2);
  bf16*   sgub  = (bf16*)alloc((size_t)2 * ISH * HID * 2);
  bf16*   sdwb  = (bf16*)alloc((size_t)HID * ISH * 2);
  bf16*   h_sh  = (bf16*)alloc((size_t)NTOK * ISH * 2);
  bf16*   h_e   = (bf16*)alloc((size_t)(NASSIGN + 128) * IMOE * 2);  // pad tail rows

  hipMemsetAsync(zpadb, 0, (HID + 64) * 2, stream);
  hipMemsetAsync(d_out, 0, (size_t)out_size * 4, stream);
  router_kernel<<<NTOK, 256, 0, stream>>>(x, gw, sgw, sg, tki, tkw);
  scatter_kernel<<<1, 256, 0, stream>>>(tki, tkw, offs, s_tok, s_wgt);
  convert_kernel<<<CVT_BLOCKS, 256, 0, stream>>>(x, w1, w2, sguw, sdw,
                                                 xb, w1b, w2b, sgub, sdwb);

  // fused gate_up: shared (swizzled) + expert (grouped)
  gemm_gu_fused<<<GU_BLOCKS, 256, 0, stream>>>(
      xb, sgub, w1b, h_sh, h_e, offs, s_tok, zpadb);
  // fused down: shared (KSPLIT=4, swizzled) + expert (KSPLIT=2)
  gemm_down_fused<<<DN_BLOCKS, 256, 0, stream>>>(
      h_sh, h_e, sdwb, w2b, out, sg, s_wgt, offs, s_tok);
}